// Round 1
// baseline (222.454 us; speedup 1.0000x reference)
//
#include <hip/hip_runtime.h>
#include <cstdint>
#include <cstddef>

#define NP  1024
#define FD  10
#define BSZ 128
#define TPB 256   // two col-halves x 128 row-owner lanes
#define RPT 8     // 128 lanes x 8 = 1024 rows per block

// One block per (pair, dir): bid = pair*2 + d.
//   d=0: rows = state(ag), cols = goal(dg)   (reward_s2g)
//   d=1: rows = goal(dg),  cols = state(ag)  (reward_g2s)
// TPB=256 occupancy experiment: lanes (tid&127) own the same 8 rows in both
// halves; half = tid>>7 scans cols [half*512, half*512+512). Per-pair VALU and
// total LDS broadcast traffic are unchanged vs the 128-thread version, but
// waves/CU goes 8 -> 16 (4 waves/SIMD) to cover the ds_read latency holes.
// Halves merge (bestd, bblk) via LDS; strict '<' keeps half 0 on ties, which
// preserves the reference first-index argmin. Half 0 then replays the winning
// 8-col block from GLOBAL (staging-chain recompute is bit-identical), recovers
// the exact first-tie index, gathers xy, reduces.
extern "C" __global__ __launch_bounds__(TPB, 4)
void chamfer_pairs(const float* __restrict__ ag, const float* __restrict__ dg,
                   const float* __restrict__ nmean, const float* __restrict__ nstd,
                   float* __restrict__ out /* [BSZ], pre-zeroed */)
{
    __shared__ __align__(16) float4 cvis[NP];   // -2 * normalized col vis (16 KB)
    __shared__ __align__(16) float  csh[NP];    // ||col vis||^2            (4 KB)
    __shared__ float mrgD[RPT * 128];           // half-1 best values       (4 KB)
    __shared__ int   mrgI[RPT * 128];           // half-1 best block ids    (4 KB)
    __shared__ float red[2];

    const int bid  = blockIdx.x;        // 0..1023
    const int pair = bid >> 1;
    const int d    = bid & 1;
    const int tid  = threadIdx.x;
    const int lane = tid & 127;         // row-owner id (shared by both halves)
    const int half = tid >> 7;          // 0: cols 0-511, 1: cols 512-1023

    const float* rowsrc = ((d == 0) ? ag : dg) + (size_t)pair * (NP * FD);
    const float* colsrc = ((d == 0) ? dg : ag) + (size_t)pair * (NP * FD);

    // -2*(std, mean) for vis features 5..8 (uniform -> scalar regs).
    const float s5 = -2.0f * nstd[5], m5 = -2.0f * nmean[5];
    const float s6 = -2.0f * nstd[6], m6 = -2.0f * nmean[6];
    const float s7 = -2.0f * nstd[7], m7 = -2.0f * nmean[7];
    const float s8 = -2.0f * nstd[8], m8 = -2.0f * nmean[8];
    const float std0 = nstd[0], mean0 = nmean[0];
    const float std1 = nstd[1], mean1 = nmean[1];

    // ---- Stage columns into LDS: t = fmaf(raw, -2s, -2m); cs = 0.25*dot(t,t)
    //      (exact chain from earlier rounds; b128 stores, conflict-light).
    for (int m = tid; m < NP; m += TPB) {
        const float* p = colsrc + (size_t)m * FD;
        float t0 = fmaf(p[5], s5, m5);
        float t1 = fmaf(p[6], s6, m6);
        float t2 = fmaf(p[7], s7, m7);
        float t3 = fmaf(p[8], s8, m8);
        cvis[m] = make_float4(t0, t1, t2, t3);
        csh[m]  = 0.25f * (t0 * t0 + t1 * t1 + t2 * t2 + t3 * t3);
    }

    // ---- Rows in registers via the proven -0.5*t route (bit-exact lineage).
    //      Both halves compute identical row state (redundant but free).
    float4 rv[RPT];
    float  rthr[RPT];
    float  bestd[RPT];
    int    bblk[RPT];
#pragma unroll
    for (int r = 0; r < RPT; ++r) {
        int n = lane + 128 * r;
        const float* p = rowsrc + (size_t)n * FD;
        float t0 = fmaf(p[5], s5, m5);
        float t1 = fmaf(p[6], s6, m6);
        float t2 = fmaf(p[7], s7, m7);
        float t3 = fmaf(p[8], s8, m8);
        rv[r] = make_float4(-0.5f * t0, -0.5f * t1, -0.5f * t2, -0.5f * t3);
        float rss = 0.25f * (t0 * t0 + t1 * t1 + t2 * t2 + t3 * t3);
        rthr[r] = 6.0f - rss;            // (rs + bestd') > 6  <=>  bestd' > 6 - rs
        bestd[r] = 3.0e38f;
        bblk[r]  = 0;
    }
    __syncthreads();

    // ---- Main loop: this half's 64 groups of 8 columns, 10 wave-uniform b128
    //      broadcasts per group, identical fmaf chain to the staging pass.
    const int g0 = half * (NP / 16);    // 64 groups per half
    for (int g = g0; g < g0 + NP / 16; ++g) {
        const int m = g * 8;
        float4 c0 = cvis[m + 0];
        float4 c1 = cvis[m + 1];
        float4 c2 = cvis[m + 2];
        float4 c3 = cvis[m + 3];
        float4 c4 = cvis[m + 4];
        float4 c5 = cvis[m + 5];
        float4 c6 = cvis[m + 6];
        float4 c7 = cvis[m + 7];
        float4 csA = *(const float4*)(csh + m);
        float4 csB = *(const float4*)(csh + m + 4);
#pragma unroll
        for (int r = 0; r < RPT; ++r) {
            float4 v = rv[r];
            float d0 = fmaf(v.x, c0.x, csA.x); d0 = fmaf(v.y, c0.y, d0); d0 = fmaf(v.z, c0.z, d0); d0 = fmaf(v.w, c0.w, d0);
            float d1 = fmaf(v.x, c1.x, csA.y); d1 = fmaf(v.y, c1.y, d1); d1 = fmaf(v.z, c1.z, d1); d1 = fmaf(v.w, c1.w, d1);
            float d2 = fmaf(v.x, c2.x, csA.z); d2 = fmaf(v.y, c2.y, d2); d2 = fmaf(v.z, c2.z, d2); d2 = fmaf(v.w, c2.w, d2);
            float d3 = fmaf(v.x, c3.x, csA.w); d3 = fmaf(v.y, c3.y, d3); d3 = fmaf(v.z, c3.z, d3); d3 = fmaf(v.w, c3.w, d3);
            float d4 = fmaf(v.x, c4.x, csB.x); d4 = fmaf(v.y, c4.y, d4); d4 = fmaf(v.z, c4.z, d4); d4 = fmaf(v.w, c4.w, d4);
            float d5 = fmaf(v.x, c5.x, csB.y); d5 = fmaf(v.y, c5.y, d5); d5 = fmaf(v.z, c5.z, d5); d5 = fmaf(v.w, c5.w, d5);
            float d6 = fmaf(v.x, c6.x, csB.z); d6 = fmaf(v.y, c6.y, d6); d6 = fmaf(v.z, c6.z, d6); d6 = fmaf(v.w, c6.w, d6);
            float d7 = fmaf(v.x, c7.x, csB.w); d7 = fmaf(v.y, c7.y, d7); d7 = fmaf(v.z, c7.z, d7); d7 = fmaf(v.w, c7.w, d7);
            // exact min of 8 (value order-invariant; no NaNs) -> v_min3 friendly
            float p0 = fminf(fminf(d0, d1), d2);
            float p1 = fminf(fminf(d3, d4), d5);
            float p2 = fminf(d6, d7);
            float bm = fminf(fminf(p0, p1), p2);
            bool lt = bm < bestd[r];       // strict < keeps FIRST block on ties
            bestd[r] = fminf(bestd[r], bm);
            bblk[r]  = lt ? m : bblk[r];
        }
    }

    // ---- Merge halves: half 1 publishes, half 0 takes strictly-smaller only
    //      (ties -> half 0 -> lower column index, matching reference argmin).
    __syncthreads();                     // main loop done; cvis/csh now dead
    if (half == 1) {
#pragma unroll
        for (int r = 0; r < RPT; ++r) {
            mrgD[r * 128 + lane] = bestd[r];   // stride-4B across lanes: conflict-free
            mrgI[r * 128 + lane] = bblk[r];
        }
    }
    __syncthreads();

    if (half == 0) {
#pragma unroll
        for (int r = 0; r < RPT; ++r) {
            float db = mrgD[r * 128 + lane];
            int   ib = mrgI[r * 128 + lane];
            if (db < bestd[r]) { bestd[r] = db; bblk[r] = ib; }
        }

        // ---- Epilogue: replay winning block from GLOBAL (staging chain
        // recompute is bit-identical for either half), recover first-tie
        // index, gather xy.
        float sum = 0.0f;
#pragma unroll
        for (int r = 0; r < RPT; ++r) {
            int n  = lane + 128 * r;
            int mb = bblk[r];
            float4 v = rv[r];
            float dd[8];
#pragma unroll
            for (int j = 0; j < 8; ++j) {
                const float* p = colsrc + (size_t)(mb + j) * FD;
                float t0 = fmaf(p[5], s5, m5);
                float t1 = fmaf(p[6], s6, m6);
                float t2 = fmaf(p[7], s7, m7);
                float t3 = fmaf(p[8], s8, m8);
                float cs = 0.25f * (t0 * t0 + t1 * t1 + t2 * t2 + t3 * t3);
                float t = fmaf(v.x, t0, cs);
                t = fmaf(v.y, t1, t);
                t = fmaf(v.z, t2, t);
                t = fmaf(v.w, t3, t);
                dd[j] = t;
            }
            int sel = 0;
#pragma unroll
            for (int j = 7; j >= 0; --j)       // descending: smallest j wins ties
                if (dd[j] == bestd[r]) sel = j;
            int idx = mb + sel;

            const float* pc = colsrc + (size_t)idx * FD;
            float gx = fmaf(pc[0], std0, mean0);
            float gy = fmaf(pc[1], std1, mean1);
            const float* pr = rowsrc + (size_t)n * FD;
            float ax = fmaf(pr[0], std0, mean0);
            float ay = fmaf(pr[1], std1, mean1);
            float dx = ax - gx;
            float dy = ay - gy;
            float dist = sqrtf(dx * dx + dy * dy);
            if (bestd[r] > rthr[r]) dist = 1.0f;   // min_d > LATENT_DIST_THRESHOLD
            sum += dist;
        }

        // ---- Reduce over the two half-0 waves.
        for (int o = 32; o > 0; o >>= 1) sum += __shfl_down(sum, o, 64);
        if ((tid & 63) == 0) red[tid >> 6] = sum;
    }
    __syncthreads();
    if (tid == 0) {
        float s = red[0] + red[1];
        // out[b] = -(sum over 4 views x 2 dirs x 1024 rows) / 8192
        atomicAdd(&out[bid >> 3], s * (-1.0f / 8192.0f));
    }
}

extern "C" void kernel_launch(void* const* d_in, const int* in_sizes, int n_in,
                              void* d_out, int out_size, void* d_ws, size_t ws_size,
                              hipStream_t stream)
{
    const float* ag = (const float*)d_in[0];   // achieved_goal (128,4,1024,10)
    const float* dg = (const float*)d_in[1];   // desired_goal  (128,4,1024,10)
    const float* nm = (const float*)d_in[2];   // norm_mean (10,)
    const float* ns = (const float*)d_in[3];   // norm_std  (10,)

    hipMemsetAsync(d_out, 0, BSZ * sizeof(float), stream);   // out is accumulated
    chamfer_pairs<<<BSZ * 4 * 2, TPB, 0, stream>>>(ag, dg, nm, ns, (float*)d_out);
}

// Round 2
// 189.245 us; speedup vs baseline: 1.1755x; 1.1755x over previous
//
#include <hip/hip_runtime.h>
#include <cstdint>
#include <cstddef>

#define NP  1024
#define FD  10
#define BSZ 128
#define TPB 256   // 4 waves; each wave owns 256 rows (8 row-tiles of 32)
#define NW  4
#define RT  8     // row-tiles per wave

// One block per (pair, dir): bid = pair*2 + d.
//   d=0: rows = state(ag), cols = goal(dg)   (reward_s2g)
//   d=1: rows = goal(dg),  cols = state(ag)  (reward_g2s)
//
// MFMA route: d(n,m) = cs_m - 2 r_n . c_m computed on the matrix pipe via
// bf16 split-3 limbs packed into K=32 (two chained 32x32x16 bf16 MFMAs):
//   K slots: [Ch.Rh][Cm.Rh][Cl.Rh][Ch.Rm] | [Cm.Rm][Ch.Rl][cs*1 x3][Cm.Rl][0]
// (C = -2c split into Ch+Cm+Cl, R = r split into Rh+Rm+Rl, cs split-3 with a
// B-side 1.0). Dropped terms Cl.Rm / Cl.Rl are <= 2^-24 relative -- same error
// class as the fp32-chain deviation that has measured absmax 0.0.
// Swapped operands (A = cols, B = rows): each lane holds 16 col-distances of
// one row (D: col=lane&31 -> our row n; row=(reg&3)+8*(reg>>2)+4*(lane>>5) ->
// our col within the 32-tile), so the row-min is a lane-local min3 tree.
// Pass 1 tracks (min value, winning col-tile) only; the epilogue re-scans the
// winning tile's 32 cols with the proven fp32 fmaf chain (first-index argmin,
// reference tie semantics within the tile), gathers xy, applies threshold.
typedef __attribute__((ext_vector_type(8)))  __bf16 bf16x8;
typedef __attribute__((ext_vector_type(16))) float  f32x16;

__device__ inline unsigned int pk2(__bf16 a, __bf16 b) {
    union { __bf16 h; unsigned short u; } ua, ub;
    ua.h = a; ub.h = b;
    return (unsigned int)ua.u | ((unsigned int)ub.u << 16);
}

__device__ inline void split3(float x, __bf16& h, __bf16& m, __bf16& l) {
    h = (__bf16)x;
    float r1 = x - (float)h;
    m = (__bf16)r1;
    float r2 = r1 - (float)m;
    l = (__bf16)r2;
}

extern "C" __global__ __launch_bounds__(TPB, 2)
void chamfer_pairs(const float* __restrict__ ag, const float* __restrict__ dg,
                   const float* __restrict__ nmean, const float* __restrict__ nstd,
                   float* __restrict__ out /* [BSZ], pre-zeroed */)
{
    // 4 fragment planes x 1024 cols x 16B. Plane f = b128 fragment f of the
    // col record: f0=(mfma1,h0)=Ch|Cm, f1=(mfma1,h1)=Cl|Ch, f2=(mfma2,h0)=Cm|Ch,
    // f3=(mfma2,h1)=csh,csm,csl|Cm|0.  64 KB total; scratch overlays after use.
    __shared__ __align__(16) unsigned int ldsA[4 * NP * 4];
    __shared__ float red[NW];

    const int bid  = blockIdx.x;        // 0..1023
    const int pair = bid >> 1;
    const int d    = bid & 1;
    const int tid  = threadIdx.x;
    const int wv   = tid >> 6;          // wave 0..3
    const int l    = tid & 63;
    const int ln   = l & 31;            // lane's row slot / col slot
    const int hh   = l >> 5;            // k-half owner

    const float* rowsrc = ((d == 0) ? ag : dg) + (size_t)pair * (NP * FD);
    const float* colsrc = ((d == 0) ? dg : ag) + (size_t)pair * (NP * FD);

    // -2*(std, mean) for vis features 5..8 (uniform -> scalar regs).
    const float s5 = -2.0f * nstd[5], m5 = -2.0f * nmean[5];
    const float s6 = -2.0f * nstd[6], m6 = -2.0f * nmean[6];
    const float s7 = -2.0f * nstd[7], m7 = -2.0f * nmean[7];
    const float s8 = -2.0f * nstd[8], m8 = -2.0f * nmean[8];
    const float std0 = nstd[0], mean0 = nmean[0];
    const float std1 = nstd[1], mean1 = nmean[1];

    // ---- Stage columns: C = t = fmaf(raw,-2s,-2m) (= -2c, proven chain),
    //      cs = 0.25*dot(t,t); split-3 and pack K-layout fragments.
    for (int m = tid; m < NP; m += TPB) {
        const float* p = colsrc + (size_t)m * FD;
        float t0 = fmaf(p[5], s5, m5);
        float t1 = fmaf(p[6], s6, m6);
        float t2 = fmaf(p[7], s7, m7);
        float t3 = fmaf(p[8], s8, m8);
        float cs = 0.25f * (t0 * t0 + t1 * t1 + t2 * t2 + t3 * t3);
        __bf16 ch0, cm0, cl0, ch1, cm1, cl1, ch2, cm2, cl2, ch3, cm3, cl3;
        __bf16 qh, qm, ql;
        split3(t0, ch0, cm0, cl0);
        split3(t1, ch1, cm1, cl1);
        split3(t2, ch2, cm2, cl2);
        split3(t3, ch3, cm3, cl3);
        split3(cs, qh, qm, ql);
        const __bf16 z = (__bf16)0.0f;
        uint4* pl = (uint4*)ldsA;
        pl[0 * NP + m] = make_uint4(pk2(ch0, ch1), pk2(ch2, ch3), pk2(cm0, cm1), pk2(cm2, cm3));
        pl[1 * NP + m] = make_uint4(pk2(cl0, cl1), pk2(cl2, cl3), pk2(ch0, ch1), pk2(ch2, ch3));
        pl[2 * NP + m] = make_uint4(pk2(cm0, cm1), pk2(cm2, cm3), pk2(ch0, ch1), pk2(ch2, ch3));
        pl[3 * NP + m] = make_uint4(pk2(qh, qm),   pk2(ql, cm0),  pk2(cm1, cm2), pk2(cm3, z));
    }

    // ---- Rows: split-3 of r = -0.5*t (= c-chain, proven lineage); assemble
    //      B fragments per k-half; threshold rthr = 6 - 0.25*dot(t,t).
    bf16x8 B1[RT], B2[RT];
    float  rthr[RT];
    const __bf16 kone = (__bf16)1.0f;
    const __bf16 kzb  = (__bf16)0.0f;
#pragma unroll
    for (int rt = 0; rt < RT; ++rt) {
        int n = wv * 256 + rt * 32 + ln;
        const float* p = rowsrc + (size_t)n * FD;
        float t0 = fmaf(p[5], s5, m5);
        float t1 = fmaf(p[6], s6, m6);
        float t2 = fmaf(p[7], s7, m7);
        float t3 = fmaf(p[8], s8, m8);
        float rss = 0.25f * (t0 * t0 + t1 * t1 + t2 * t2 + t3 * t3);
        rthr[rt] = 6.0f - rss;
        float r0 = -0.5f * t0, r1 = -0.5f * t1, r2 = -0.5f * t2, r3 = -0.5f * t3;
        __bf16 rh0, rm0, rl0, rh1, rm1, rl1, rh2, rm2, rl2, rh3, rm3, rl3;
        split3(r0, rh0, rm0, rl0);
        split3(r1, rh1, rm1, rl1);
        split3(r2, rh2, rm2, rl2);
        split3(r3, rh3, rm3, rl3);
        bf16x8 b1, b2;
        b1[0] = rh0; b1[1] = rh1; b1[2] = rh2; b1[3] = rh3;
        b1[4] = hh ? rm0 : rh0;
        b1[5] = hh ? rm1 : rh1;
        b1[6] = hh ? rm2 : rh2;
        b1[7] = hh ? rm3 : rh3;
        b2[0] = hh ? kone : rm0;
        b2[1] = hh ? kone : rm1;
        b2[2] = hh ? kone : rm2;
        b2[3] = hh ? rl0  : rm3;
        b2[4] = hh ? rl1  : rl0;
        b2[5] = hh ? rl2  : rl1;
        b2[6] = hh ? rl3  : rl2;
        b2[7] = hh ? kzb  : rl3;
        B1[rt] = b1; B2[rt] = b2;
    }
    __syncthreads();

    // ---- Pass 1: 32 col-tiles; per tile 2 chained MFMAs -> 16 distances/lane
    //      (cols of row n = wv*256 + rt*32 + ln), lane-local min3 tree, track
    //      (min, tile).
    f32x16 kz = {0.0f,0.0f,0.0f,0.0f,0.0f,0.0f,0.0f,0.0f,
                 0.0f,0.0f,0.0f,0.0f,0.0f,0.0f,0.0f,0.0f};
    float runmin[RT];
    int   runct[RT];
#pragma unroll
    for (int rt = 0; rt < RT; ++rt) { runmin[rt] = 3.0e38f; runct[rt] = 0; }

    const char* aBase1 = (const char*)ldsA + (size_t)hh * (NP * 16) + (size_t)ln * 16;
    const char* aBase2 = aBase1 + 2 * (NP * 16);

    for (int ct = 0; ct < 32; ++ct) {
        const bf16x8 a1 = *(const bf16x8*)(aBase1 + (size_t)ct * 512);
        const bf16x8 a2 = *(const bf16x8*)(aBase2 + (size_t)ct * 512);
#pragma unroll
        for (int rt = 0; rt < RT; ++rt) {
            f32x16 acc = __builtin_amdgcn_mfma_f32_32x32x16_bf16(a1, B1[rt], kz, 0, 0, 0);
            acc = __builtin_amdgcn_mfma_f32_32x32x16_bf16(a2, B2[rt], acc, 0, 0, 0);
            float u0 = fminf(fminf(acc[0],  acc[1]),  fminf(acc[2],  acc[3]));
            float u1 = fminf(fminf(acc[4],  acc[5]),  fminf(acc[6],  acc[7]));
            float u2 = fminf(fminf(acc[8],  acc[9]),  fminf(acc[10], acc[11]));
            float u3 = fminf(fminf(acc[12], acc[13]), fminf(acc[14], acc[15]));
            float mn = fminf(fminf(u0, u1), fminf(u2, u3));
            bool lt = mn < runmin[rt];         // strict < keeps FIRST tile
            runmin[rt] = fminf(runmin[rt], mn);
            runct[rt]  = lt ? ct : runct[rt];
        }
    }
    __syncthreads();   // all A-plane reads done; ldsA reusable as scratch

    // ---- Merge k-halves (lanes l and l^32 cover interleaved col-quads of the
    //      same row): lexicographic (value, tile) with strict preference, then
    //      publish (tile, thr) per row to scratch.
    int*   sCt  = (int*)ldsA;          // [1024]
    float* sThr = (float*)(ldsA + NP); // [1024]
#pragma unroll
    for (int rt = 0; rt < RT; ++rt) {
        float ov = __shfl_xor(runmin[rt], 32);
        int   oc = __shfl_xor(runct[rt], 32);
        bool take = (ov < runmin[rt]) || (ov == runmin[rt] && oc < runct[rt]);
        int mc = take ? oc : runct[rt];
        if (hh == 0) {
            int n = wv * 256 + rt * 32 + ln;
            sCt[n]  = mc;
            sThr[n] = rthr[rt];
        }
    }
    __syncthreads();

    // ---- Epilogue: per row, fp32 re-scan of the winning 32-col tile from
    //      GLOBAL with the proven fmaf chain; first-index argmin (strict <),
    //      xy gather, threshold.
    float sum = 0.0f;
    for (int q = 0; q < 4; ++q) {
        int n = tid * 4 + q;
        int ct = sCt[n];
        float thr = sThr[n];
        const float* pr = rowsrc + (size_t)n * FD;
        float t0 = fmaf(pr[5], s5, m5);
        float t1 = fmaf(pr[6], s6, m6);
        float t2 = fmaf(pr[7], s7, m7);
        float t3 = fmaf(pr[8], s8, m8);
        float vx = -0.5f * t0, vy = -0.5f * t1, vz = -0.5f * t2, vw = -0.5f * t3;
        float best = 3.0e38f;
        int bidx = 0;
        const int mbase = ct * 32;
#pragma unroll 4
        for (int j = 0; j < 32; ++j) {
            const float* pc = colsrc + (size_t)(mbase + j) * FD;
            float c0 = fmaf(pc[5], s5, m5);
            float c1 = fmaf(pc[6], s6, m6);
            float c2 = fmaf(pc[7], s7, m7);
            float c3 = fmaf(pc[8], s8, m8);
            float cs = 0.25f * (c0 * c0 + c1 * c1 + c2 * c2 + c3 * c3);
            float dd = fmaf(vx, c0, cs);
            dd = fmaf(vy, c1, dd);
            dd = fmaf(vz, c2, dd);
            dd = fmaf(vw, c3, dd);
            if (dd < best) { best = dd; bidx = mbase + j; }  // first idx on ties
        }
        const float* pw = colsrc + (size_t)bidx * FD;
        float gx = fmaf(pw[0], std0, mean0);
        float gy = fmaf(pw[1], std1, mean1);
        float ax = fmaf(pr[0], std0, mean0);
        float ay = fmaf(pr[1], std1, mean1);
        float dx = ax - gx;
        float dy = ay - gy;
        float dist = sqrtf(dx * dx + dy * dy);
        if (best > thr) dist = 1.0f;     // min_d > LATENT_DIST_THRESHOLD
        sum += dist;
    }

    // ---- Reduce: wave shuffle, cross-wave LDS, one atomic per block.
    for (int o = 32; o > 0; o >>= 1) sum += __shfl_down(sum, o, 64);
    if ((tid & 63) == 0) red[tid >> 6] = sum;
    __syncthreads();
    if (tid == 0) {
        float s = red[0] + red[1] + red[2] + red[3];
        // out[b] = -(sum over 4 views x 2 dirs x 1024 rows) / 8192
        atomicAdd(&out[bid >> 3], s * (-1.0f / 8192.0f));
    }
}

extern "C" void kernel_launch(void* const* d_in, const int* in_sizes, int n_in,
                              void* d_out, int out_size, void* d_ws, size_t ws_size,
                              hipStream_t stream)
{
    const float* ag = (const float*)d_in[0];   // achieved_goal (128,4,1024,10)
    const float* dg = (const float*)d_in[1];   // desired_goal  (128,4,1024,10)
    const float* nm = (const float*)d_in[2];   // norm_mean (10,)
    const float* ns = (const float*)d_in[3];   // norm_std  (10,)

    hipMemsetAsync(d_out, 0, BSZ * sizeof(float), stream);   // out is accumulated
    chamfer_pairs<<<BSZ * 4 * 2, TPB, 0, stream>>>(ag, dg, nm, ns, (float*)d_out);
}

// Round 3
// 184.732 us; speedup vs baseline: 1.2042x; 1.0244x over previous
//
#include <hip/hip_runtime.h>
#include <cstdint>
#include <cstddef>

#define NP  1024
#define FD  10
#define BSZ 128
#define TPB 256   // 4 waves; each wave owns 256 rows (8 row-tiles of 32)
#define NW  4
#define RT  8     // row-tiles per wave

// One block per (pair, dir): bid = pair*2 + d.
//   d=0: rows = state(ag), cols = goal(dg)   (reward_s2g)
//   d=1: rows = goal(dg),  cols = state(ag)  (reward_g2s)
//
// MFMA route, R3 layout: d(n,m) = cs_m - 2 r_n . c_m on the matrix pipe via
// bf16 split-3 limbs in K=32 (two chained 32x32x16 bf16 MFMAs). Term set is
// IDENTICAL to the R2 kernel that measured absmax 0.0 (ChRh, CmRh, ClRh,
// ChRm, CmRm, ChRl, CmRl + cs split-3; drops only ClRm/ClRl <= 2^-24 rel).
// K-slot reassignment packs A-side data into 3 LDS planes (48 KB, was 64 KB):
//   P0 = [Ch|Cm]  -- MFMA1, BOTH k-halves (B supplies Rh then Rm)
//   P1 = [Cl|Ch]  -- MFMA2 k-half 0       (B supplies Rh then Rl)
//   P2 = [Cm|csh,csm,csl,0] -- MFMA2 k-half 1 (B supplies Rl then 1,1,1,0)
// -> 3 blocks/CU (was 2), 3 waves/SIMD to cover MFMA+tree dependency chains.
// Swapped operands (A = cols, B = rows): lane holds 16 col-distances of one
// row; row-min is a lane-local min3 tree (8 ops). Pass 1 tracks (min, tile);
// epilogue re-scans the winning tile's 32 cols with the proven fp32 fmaf
// chain (first-index argmin, reference tie semantics), gathers xy, thresholds.
typedef __attribute__((ext_vector_type(8)))  __bf16 bf16x8;
typedef __attribute__((ext_vector_type(16))) float  f32x16;

__device__ inline unsigned int pk2(__bf16 a, __bf16 b) {
    union { __bf16 h; unsigned short u; } ua, ub;
    ua.h = a; ub.h = b;
    return (unsigned int)ua.u | ((unsigned int)ub.u << 16);
}

__device__ inline void split3(float x, __bf16& h, __bf16& m, __bf16& l) {
    h = (__bf16)x;
    float r1 = x - (float)h;    // exact (h carries x's exponent, 8-bit mantissa)
    m = (__bf16)r1;
    float r2 = r1 - (float)m;   // exact
    l = (__bf16)r2;
}

__device__ inline float min3f(float a, float b, float c) {
    return fminf(fminf(a, b), c);   // fuses to v_min3_f32; order-invariant exact
}

extern "C" __global__ __launch_bounds__(TPB, 3)
void chamfer_pairs(const float* __restrict__ ag, const float* __restrict__ dg,
                   const float* __restrict__ nmean, const float* __restrict__ nstd,
                   float* __restrict__ out /* [BSZ], pre-zeroed */)
{
    // 3 fragment planes x 1024 cols x 16B = 48 KB; scratch overlays after use.
    __shared__ __align__(16) unsigned int ldsA[3 * NP * 4];
    __shared__ float red[NW];

    const int bid  = blockIdx.x;        // 0..1023
    const int pair = bid >> 1;
    const int d    = bid & 1;
    const int tid  = threadIdx.x;
    const int wv   = tid >> 6;          // wave 0..3
    const int l    = tid & 63;
    const int ln   = l & 31;            // lane's row slot / col slot
    const int hh   = l >> 5;            // k-half owner

    const float* rowsrc = ((d == 0) ? ag : dg) + (size_t)pair * (NP * FD);
    const float* colsrc = ((d == 0) ? dg : ag) + (size_t)pair * (NP * FD);

    // -2*(std, mean) for vis features 5..8 (uniform -> scalar regs).
    const float s5 = -2.0f * nstd[5], m5 = -2.0f * nmean[5];
    const float s6 = -2.0f * nstd[6], m6 = -2.0f * nmean[6];
    const float s7 = -2.0f * nstd[7], m7 = -2.0f * nmean[7];
    const float s8 = -2.0f * nstd[8], m8 = -2.0f * nmean[8];
    const float std0 = nstd[0], mean0 = nmean[0];
    const float std1 = nstd[1], mean1 = nmean[1];

    // ---- Stage columns: C = t = fmaf(raw,-2s,-2m) (= -2c, proven chain),
    //      cs = 0.25*dot(t,t); split-3 and pack the 3 K-layout planes.
    for (int m = tid; m < NP; m += TPB) {
        const float* p = colsrc + (size_t)m * FD;
        float t0 = fmaf(p[5], s5, m5);
        float t1 = fmaf(p[6], s6, m6);
        float t2 = fmaf(p[7], s7, m7);
        float t3 = fmaf(p[8], s8, m8);
        float cs = 0.25f * (t0 * t0 + t1 * t1 + t2 * t2 + t3 * t3);
        __bf16 ch0, cm0, cl0, ch1, cm1, cl1, ch2, cm2, cl2, ch3, cm3, cl3;
        __bf16 qh, qm, ql;
        split3(t0, ch0, cm0, cl0);
        split3(t1, ch1, cm1, cl1);
        split3(t2, ch2, cm2, cl2);
        split3(t3, ch3, cm3, cl3);
        split3(cs, qh, qm, ql);
        const __bf16 z = (__bf16)0.0f;
        unsigned int chA = pk2(ch0, ch1), chB = pk2(ch2, ch3);
        unsigned int cmA = pk2(cm0, cm1), cmB = pk2(cm2, cm3);
        unsigned int clA = pk2(cl0, cl1), clB = pk2(cl2, cl3);
        uint4* pl = (uint4*)ldsA;
        pl[0 * NP + m] = make_uint4(chA, chB, cmA, cmB);            // P0 = [Ch|Cm]
        pl[1 * NP + m] = make_uint4(clA, clB, chA, chB);            // P1 = [Cl|Ch]
        pl[2 * NP + m] = make_uint4(cmA, cmB, pk2(qh, qm), pk2(ql, z)); // P2 = [Cm|cs3,0]
    }

    // ---- Rows: split-3 of r = -0.5*t (proven lineage); B fragments per
    //      k-half for the new K layout; threshold rthr = 6 - 0.25*dot(t,t).
    bf16x8 B1[RT], B2[RT];
    float  rthr[RT];
    const __bf16 kone = (__bf16)1.0f;
    const __bf16 kzb  = (__bf16)0.0f;
#pragma unroll
    for (int rt = 0; rt < RT; ++rt) {
        int n = wv * 256 + rt * 32 + ln;
        const float* p = rowsrc + (size_t)n * FD;
        float t0 = fmaf(p[5], s5, m5);
        float t1 = fmaf(p[6], s6, m6);
        float t2 = fmaf(p[7], s7, m7);
        float t3 = fmaf(p[8], s8, m8);
        float rss = 0.25f * (t0 * t0 + t1 * t1 + t2 * t2 + t3 * t3);
        rthr[rt] = 6.0f - rss;
        float r0 = -0.5f * t0, r1 = -0.5f * t1, r2 = -0.5f * t2, r3 = -0.5f * t3;
        __bf16 rh0, rm0, rl0, rh1, rm1, rl1, rh2, rm2, rl2, rh3, rm3, rl3;
        split3(r0, rh0, rm0, rl0);
        split3(r1, rh1, rm1, rl1);
        split3(r2, rh2, rm2, rl2);
        split3(r3, rh3, rm3, rl3);
        // MFMA1: K0-7 = Ch.Rh, Cm.Rh ; K8-15 = Ch.Rm, Cm.Rm  (A = P0 both halves)
        __bf16 p0 = hh ? rm0 : rh0;
        __bf16 p1 = hh ? rm1 : rh1;
        __bf16 p2 = hh ? rm2 : rh2;
        __bf16 p3 = hh ? rm3 : rh3;
        bf16x8 b1;
        b1[0] = p0; b1[1] = p1; b1[2] = p2; b1[3] = p3;
        b1[4] = p0; b1[5] = p1; b1[6] = p2; b1[7] = p3;
        // MFMA2: K0-7 = Cl.Rh, Ch.Rl (A=P1) ; K8-15 = Cm.Rl, cs*1 (A=P2)
        __bf16 q0 = hh ? rl0 : rh0;
        __bf16 q1 = hh ? rl1 : rh1;
        __bf16 q2 = hh ? rl2 : rh2;
        __bf16 q3 = hh ? rl3 : rh3;
        bf16x8 b2;
        b2[0] = q0; b2[1] = q1; b2[2] = q2; b2[3] = q3;
        b2[4] = hh ? kone : rl0;
        b2[5] = hh ? kone : rl1;
        b2[6] = hh ? kone : rl2;
        b2[7] = hh ? kzb  : rl3;
        B1[rt] = b1; B2[rt] = b2;
    }
    __syncthreads();

    // ---- Pass 1: 32 col-tiles; per tile 2 chained MFMAs -> 16 distances/lane,
    //      two concurrent rt-chains for MFMA-latency overlap, min3 tree, track
    //      (min, tile).
    f32x16 kz = {0.0f,0.0f,0.0f,0.0f,0.0f,0.0f,0.0f,0.0f,
                 0.0f,0.0f,0.0f,0.0f,0.0f,0.0f,0.0f,0.0f};
    float runmin[RT];
    int   runct[RT];
#pragma unroll
    for (int rt = 0; rt < RT; ++rt) { runmin[rt] = 3.0e38f; runct[rt] = 0; }

    const char* aBase1 = (const char*)ldsA + (size_t)ln * 16;                    // P0
    const char* aBase2 = (const char*)ldsA + (size_t)(1 + hh) * (NP * 16) + (size_t)ln * 16;

    for (int ct = 0; ct < 32; ++ct) {
        const bf16x8 a1 = *(const bf16x8*)(aBase1 + (size_t)ct * 512);
        const bf16x8 a2 = *(const bf16x8*)(aBase2 + (size_t)ct * 512);
#pragma unroll
        for (int rt = 0; rt < RT; rt += 2) {
            f32x16 accA = __builtin_amdgcn_mfma_f32_32x32x16_bf16(a1, B1[rt],     kz, 0, 0, 0);
            f32x16 accB = __builtin_amdgcn_mfma_f32_32x32x16_bf16(a1, B1[rt + 1], kz, 0, 0, 0);
            accA = __builtin_amdgcn_mfma_f32_32x32x16_bf16(a2, B2[rt],     accA, 0, 0, 0);
            accB = __builtin_amdgcn_mfma_f32_32x32x16_bf16(a2, B2[rt + 1], accB, 0, 0, 0);
            {
                float u0 = min3f(accA[0],  accA[1],  accA[2]);
                float u1 = min3f(accA[3],  accA[4],  accA[5]);
                float u2 = min3f(accA[6],  accA[7],  accA[8]);
                float u3 = min3f(accA[9],  accA[10], accA[11]);
                float u4 = min3f(accA[12], accA[13], accA[14]);
                float mn = fminf(min3f(u0, u1, u2), min3f(u3, u4, accA[15]));
                bool lt = mn < runmin[rt];         // strict < keeps FIRST tile
                runmin[rt] = fminf(runmin[rt], mn);
                runct[rt]  = lt ? ct : runct[rt];
            }
            {
                float u0 = min3f(accB[0],  accB[1],  accB[2]);
                float u1 = min3f(accB[3],  accB[4],  accB[5]);
                float u2 = min3f(accB[6],  accB[7],  accB[8]);
                float u3 = min3f(accB[9],  accB[10], accB[11]);
                float u4 = min3f(accB[12], accB[13], accB[14]);
                float mn = fminf(min3f(u0, u1, u2), min3f(u3, u4, accB[15]));
                bool lt = mn < runmin[rt + 1];
                runmin[rt + 1] = fminf(runmin[rt + 1], mn);
                runct[rt + 1]  = lt ? ct : runct[rt + 1];
            }
        }
    }
    __syncthreads();   // all A-plane reads done; ldsA reusable as scratch

    // ---- Merge k-halves (lanes l and l^32 cover interleaved col-quads of the
    //      same row): lexicographic (value, tile) with strict preference, then
    //      publish (tile, thr) per row to scratch.
    int*   sCt  = (int*)ldsA;          // [1024]
    float* sThr = (float*)(ldsA + NP); // [1024]
#pragma unroll
    for (int rt = 0; rt < RT; ++rt) {
        float ov = __shfl_xor(runmin[rt], 32);
        int   oc = __shfl_xor(runct[rt], 32);
        bool take = (ov < runmin[rt]) || (ov == runmin[rt] && oc < runct[rt]);
        int mc = take ? oc : runct[rt];
        if (hh == 0) {
            int n = wv * 256 + rt * 32 + ln;
            sCt[n]  = mc;
            sThr[n] = rthr[rt];
        }
    }
    __syncthreads();

    // ---- Epilogue: per row, fp32 re-scan of the winning 32-col tile from
    //      GLOBAL with the proven fmaf chain; first-index argmin (strict <),
    //      xy gather, threshold.
    float sum = 0.0f;
    for (int q = 0; q < 4; ++q) {
        int n = tid * 4 + q;
        int ct = sCt[n];
        float thr = sThr[n];
        const float* pr = rowsrc + (size_t)n * FD;
        float t0 = fmaf(pr[5], s5, m5);
        float t1 = fmaf(pr[6], s6, m6);
        float t2 = fmaf(pr[7], s7, m7);
        float t3 = fmaf(pr[8], s8, m8);
        float vx = -0.5f * t0, vy = -0.5f * t1, vz = -0.5f * t2, vw = -0.5f * t3;
        float best = 3.0e38f;
        int bidx = 0;
        const int mbase = ct * 32;
#pragma unroll 4
        for (int j = 0; j < 32; ++j) {
            const float* pc = colsrc + (size_t)(mbase + j) * FD;
            float c0 = fmaf(pc[5], s5, m5);
            float c1 = fmaf(pc[6], s6, m6);
            float c2 = fmaf(pc[7], s7, m7);
            float c3 = fmaf(pc[8], s8, m8);
            float cs = 0.25f * (c0 * c0 + c1 * c1 + c2 * c2 + c3 * c3);
            float dd = fmaf(vx, c0, cs);
            dd = fmaf(vy, c1, dd);
            dd = fmaf(vz, c2, dd);
            dd = fmaf(vw, c3, dd);
            if (dd < best) { best = dd; bidx = mbase + j; }  // first idx on ties
        }
        const float* pw = colsrc + (size_t)bidx * FD;
        float gx = fmaf(pw[0], std0, mean0);
        float gy = fmaf(pw[1], std1, mean1);
        float ax = fmaf(pr[0], std0, mean0);
        float ay = fmaf(pr[1], std1, mean1);
        float dx = ax - gx;
        float dy = ay - gy;
        float dist = sqrtf(dx * dx + dy * dy);
        if (best > thr) dist = 1.0f;     // min_d > LATENT_DIST_THRESHOLD
        sum += dist;
    }

    // ---- Reduce: wave shuffle, cross-wave LDS, one atomic per block.
    for (int o = 32; o > 0; o >>= 1) sum += __shfl_down(sum, o, 64);
    if ((tid & 63) == 0) red[tid >> 6] = sum;
    __syncthreads();
    if (tid == 0) {
        float s = red[0] + red[1] + red[2] + red[3];
        // out[b] = -(sum over 4 views x 2 dirs x 1024 rows) / 8192
        atomicAdd(&out[bid >> 3], s * (-1.0f / 8192.0f));
    }
}

extern "C" void kernel_launch(void* const* d_in, const int* in_sizes, int n_in,
                              void* d_out, int out_size, void* d_ws, size_t ws_size,
                              hipStream_t stream)
{
    const float* ag = (const float*)d_in[0];   // achieved_goal (128,4,1024,10)
    const float* dg = (const float*)d_in[1];   // desired_goal  (128,4,1024,10)
    const float* nm = (const float*)d_in[2];   // norm_mean (10,)
    const float* ns = (const float*)d_in[3];   // norm_std  (10,)

    hipMemsetAsync(d_out, 0, BSZ * sizeof(float), stream);   // out is accumulated
    chamfer_pairs<<<BSZ * 4 * 2, TPB, 0, stream>>>(ag, dg, nm, ns, (float*)d_out);
}

// Round 4
// 175.786 us; speedup vs baseline: 1.2655x; 1.0509x over previous
//
#include <hip/hip_runtime.h>
#include <cstdint>
#include <cstddef>

#define NP  1024
#define FD  10
#define BSZ 128
#define TPB 512   // 8 waves; each wave owns 128 rows (4 row-tiles of 32)
#define NW  8
#define RT  4     // row-tiles per wave

// One block per (pair, dir): bid = pair*2 + d.
//   d=0: rows = state(ag), cols = goal(dg)   (reward_s2g)
//   d=1: rows = goal(dg),  cols = state(ag)  (reward_g2s)
//
// MFMA route, R4 = R3 numerics with 8 waves/block for occupancy.
// d(n,m) = cs_m - 2 r_n . c_m on the matrix pipe via bf16 split-3 limbs in
// K=32 (two chained 32x32x16 bf16 MFMAs). Term set IDENTICAL to the R2/R3
// kernels that measured absmax 0.0 (ChRh, CmRh, ClRh, ChRm, CmRm, ChRl,
// CmRl + cs split-3; drops only ClRm/ClRl <= 2^-24 rel).
// LDS planes (48 KB):
//   P0 = [Ch|Cm]  -- MFMA1, BOTH k-halves (B supplies Rh then Rm)
//   P1 = [Cl|Ch]  -- MFMA2 k-half 0       (B supplies Rh then Rl)
//   P2 = [Cm|csh,csm,csl,0] -- MFMA2 k-half 1 (B supplies Rl then 1,1,1,0)
// TPB=512: 2 blocks/CU x 8 waves = 16 waves/CU (the VGPR<=128 cap), double
// R3's ~8.5 resident waves, to cover the mfma->mfma(acc)->min-tree chains.
// Swapped operands (A = cols, B = rows): lane holds 16 col-distances of one
// row; row-min is a lane-local min3 tree. Pass 1 tracks (min, tile);
// epilogue re-scans the winning tile's 32 cols with the proven fp32 fmaf
// chain (first-index argmin, reference tie semantics), gathers xy, thresholds.
typedef __attribute__((ext_vector_type(8)))  __bf16 bf16x8;
typedef __attribute__((ext_vector_type(16))) float  f32x16;

__device__ inline unsigned int pk2(__bf16 a, __bf16 b) {
    union { __bf16 h; unsigned short u; } ua, ub;
    ua.h = a; ub.h = b;
    return (unsigned int)ua.u | ((unsigned int)ub.u << 16);
}

__device__ inline void split3(float x, __bf16& h, __bf16& m, __bf16& l) {
    h = (__bf16)x;
    float r1 = x - (float)h;    // exact (h carries x's exponent, 8-bit mantissa)
    m = (__bf16)r1;
    float r2 = r1 - (float)m;   // exact
    l = (__bf16)r2;
}

__device__ inline float min3f(float a, float b, float c) {
    return fminf(fminf(a, b), c);   // fuses to v_min3_f32; order-invariant exact
}

extern "C" __global__ __launch_bounds__(TPB, 4)
void chamfer_pairs(const float* __restrict__ ag, const float* __restrict__ dg,
                   const float* __restrict__ nmean, const float* __restrict__ nstd,
                   float* __restrict__ out /* [BSZ], pre-zeroed */)
{
    // 3 fragment planes x 1024 cols x 16B = 48 KB; scratch overlays after use.
    __shared__ __align__(16) unsigned int ldsA[3 * NP * 4];
    __shared__ float red[NW];

    const int bid  = blockIdx.x;        // 0..1023
    const int pair = bid >> 1;
    const int d    = bid & 1;
    const int tid  = threadIdx.x;
    const int wv   = tid >> 6;          // wave 0..7
    const int l    = tid & 63;
    const int ln   = l & 31;            // lane's row slot / col slot
    const int hh   = l >> 5;            // k-half owner

    const float* rowsrc = ((d == 0) ? ag : dg) + (size_t)pair * (NP * FD);
    const float* colsrc = ((d == 0) ? dg : ag) + (size_t)pair * (NP * FD);

    // -2*(std, mean) for vis features 5..8 (uniform -> scalar regs).
    const float s5 = -2.0f * nstd[5], m5 = -2.0f * nmean[5];
    const float s6 = -2.0f * nstd[6], m6 = -2.0f * nmean[6];
    const float s7 = -2.0f * nstd[7], m7 = -2.0f * nmean[7];
    const float s8 = -2.0f * nstd[8], m8 = -2.0f * nmean[8];
    const float std0 = nstd[0], mean0 = nmean[0];
    const float std1 = nstd[1], mean1 = nmean[1];

    // ---- Stage columns: C = t = fmaf(raw,-2s,-2m) (= -2c, proven chain),
    //      cs = 0.25*dot(t,t); split-3 and pack the 3 K-layout planes.
    for (int m = tid; m < NP; m += TPB) {
        const float* p = colsrc + (size_t)m * FD;
        float t0 = fmaf(p[5], s5, m5);
        float t1 = fmaf(p[6], s6, m6);
        float t2 = fmaf(p[7], s7, m7);
        float t3 = fmaf(p[8], s8, m8);
        float cs = 0.25f * (t0 * t0 + t1 * t1 + t2 * t2 + t3 * t3);
        __bf16 ch0, cm0, cl0, ch1, cm1, cl1, ch2, cm2, cl2, ch3, cm3, cl3;
        __bf16 qh, qm, ql;
        split3(t0, ch0, cm0, cl0);
        split3(t1, ch1, cm1, cl1);
        split3(t2, ch2, cm2, cl2);
        split3(t3, ch3, cm3, cl3);
        split3(cs, qh, qm, ql);
        const __bf16 z = (__bf16)0.0f;
        unsigned int chA = pk2(ch0, ch1), chB = pk2(ch2, ch3);
        unsigned int cmA = pk2(cm0, cm1), cmB = pk2(cm2, cm3);
        unsigned int clA = pk2(cl0, cl1), clB = pk2(cl2, cl3);
        uint4* pl = (uint4*)ldsA;
        pl[0 * NP + m] = make_uint4(chA, chB, cmA, cmB);            // P0 = [Ch|Cm]
        pl[1 * NP + m] = make_uint4(clA, clB, chA, chB);            // P1 = [Cl|Ch]
        pl[2 * NP + m] = make_uint4(cmA, cmB, pk2(qh, qm), pk2(ql, z)); // P2 = [Cm|cs3,0]
    }

    // ---- Rows: split-3 of r = -0.5*t (proven lineage); B fragments per
    //      k-half for the K layout; threshold rthr = 6 - 0.25*dot(t,t).
    bf16x8 B1[RT], B2[RT];
    float  rthr[RT];
    const __bf16 kone = (__bf16)1.0f;
    const __bf16 kzb  = (__bf16)0.0f;
#pragma unroll
    for (int rt = 0; rt < RT; ++rt) {
        int n = wv * 128 + rt * 32 + ln;
        const float* p = rowsrc + (size_t)n * FD;
        float t0 = fmaf(p[5], s5, m5);
        float t1 = fmaf(p[6], s6, m6);
        float t2 = fmaf(p[7], s7, m7);
        float t3 = fmaf(p[8], s8, m8);
        float rss = 0.25f * (t0 * t0 + t1 * t1 + t2 * t2 + t3 * t3);
        rthr[rt] = 6.0f - rss;
        float r0 = -0.5f * t0, r1 = -0.5f * t1, r2 = -0.5f * t2, r3 = -0.5f * t3;
        __bf16 rh0, rm0, rl0, rh1, rm1, rl1, rh2, rm2, rl2, rh3, rm3, rl3;
        split3(r0, rh0, rm0, rl0);
        split3(r1, rh1, rm1, rl1);
        split3(r2, rh2, rm2, rl2);
        split3(r3, rh3, rm3, rl3);
        // MFMA1: K0-7 = Ch.Rh, Cm.Rh ; K8-15 = Ch.Rm, Cm.Rm  (A = P0 both halves)
        __bf16 p0 = hh ? rm0 : rh0;
        __bf16 p1 = hh ? rm1 : rh1;
        __bf16 p2 = hh ? rm2 : rh2;
        __bf16 p3 = hh ? rm3 : rh3;
        bf16x8 b1;
        b1[0] = p0; b1[1] = p1; b1[2] = p2; b1[3] = p3;
        b1[4] = p0; b1[5] = p1; b1[6] = p2; b1[7] = p3;
        // MFMA2: K0-7 = Cl.Rh, Ch.Rl (A=P1) ; K8-15 = Cm.Rl, cs*1 (A=P2)
        __bf16 q0 = hh ? rl0 : rh0;
        __bf16 q1 = hh ? rl1 : rh1;
        __bf16 q2 = hh ? rl2 : rh2;
        __bf16 q3 = hh ? rl3 : rh3;
        bf16x8 b2;
        b2[0] = q0; b2[1] = q1; b2[2] = q2; b2[3] = q3;
        b2[4] = hh ? kone : rl0;
        b2[5] = hh ? kone : rl1;
        b2[6] = hh ? kone : rl2;
        b2[7] = hh ? kzb  : rl3;
        B1[rt] = b1; B2[rt] = b2;
    }
    __syncthreads();

    // ---- Pass 1: 32 col-tiles; per tile 2 chained MFMAs -> 16 distances/lane,
    //      two concurrent rt-chains for MFMA-latency overlap, min3 tree, track
    //      (min, tile).
    f32x16 kz = {0.0f,0.0f,0.0f,0.0f,0.0f,0.0f,0.0f,0.0f,
                 0.0f,0.0f,0.0f,0.0f,0.0f,0.0f,0.0f,0.0f};
    float runmin[RT];
    int   runct[RT];
#pragma unroll
    for (int rt = 0; rt < RT; ++rt) { runmin[rt] = 3.0e38f; runct[rt] = 0; }

    const char* aBase1 = (const char*)ldsA + (size_t)ln * 16;                    // P0
    const char* aBase2 = (const char*)ldsA + (size_t)(1 + hh) * (NP * 16) + (size_t)ln * 16;

    for (int ct = 0; ct < 32; ++ct) {
        const bf16x8 a1 = *(const bf16x8*)(aBase1 + (size_t)ct * 512);
        const bf16x8 a2 = *(const bf16x8*)(aBase2 + (size_t)ct * 512);
#pragma unroll
        for (int rt = 0; rt < RT; rt += 2) {
            f32x16 accA = __builtin_amdgcn_mfma_f32_32x32x16_bf16(a1, B1[rt],     kz, 0, 0, 0);
            f32x16 accB = __builtin_amdgcn_mfma_f32_32x32x16_bf16(a1, B1[rt + 1], kz, 0, 0, 0);
            accA = __builtin_amdgcn_mfma_f32_32x32x16_bf16(a2, B2[rt],     accA, 0, 0, 0);
            accB = __builtin_amdgcn_mfma_f32_32x32x16_bf16(a2, B2[rt + 1], accB, 0, 0, 0);
            {
                float u0 = min3f(accA[0],  accA[1],  accA[2]);
                float u1 = min3f(accA[3],  accA[4],  accA[5]);
                float u2 = min3f(accA[6],  accA[7],  accA[8]);
                float u3 = min3f(accA[9],  accA[10], accA[11]);
                float u4 = min3f(accA[12], accA[13], accA[14]);
                float mn = fminf(min3f(u0, u1, u2), min3f(u3, u4, accA[15]));
                bool lt = mn < runmin[rt];         // strict < keeps FIRST tile
                runmin[rt] = fminf(runmin[rt], mn);
                runct[rt]  = lt ? ct : runct[rt];
            }
            {
                float u0 = min3f(accB[0],  accB[1],  accB[2]);
                float u1 = min3f(accB[3],  accB[4],  accB[5]);
                float u2 = min3f(accB[6],  accB[7],  accB[8]);
                float u3 = min3f(accB[9],  accB[10], accB[11]);
                float u4 = min3f(accB[12], accB[13], accB[14]);
                float mn = fminf(min3f(u0, u1, u2), min3f(u3, u4, accB[15]));
                bool lt = mn < runmin[rt + 1];
                runmin[rt + 1] = fminf(runmin[rt + 1], mn);
                runct[rt + 1]  = lt ? ct : runct[rt + 1];
            }
        }
    }
    __syncthreads();   // all A-plane reads done; ldsA reusable as scratch

    // ---- Merge k-halves (lanes l and l^32 cover interleaved col-quads of the
    //      same row): lexicographic (value, tile) with strict preference, then
    //      publish (tile, thr) per row to scratch.
    int*   sCt  = (int*)ldsA;          // [1024]
    float* sThr = (float*)(ldsA + NP); // [1024]
#pragma unroll
    for (int rt = 0; rt < RT; ++rt) {
        float ov = __shfl_xor(runmin[rt], 32);
        int   oc = __shfl_xor(runct[rt], 32);
        bool take = (ov < runmin[rt]) || (ov == runmin[rt] && oc < runct[rt]);
        int mc = take ? oc : runct[rt];
        if (hh == 0) {
            int n = wv * 128 + rt * 32 + ln;
            sCt[n]  = mc;
            sThr[n] = rthr[rt];
        }
    }
    __syncthreads();

    // ---- Epilogue: per row, fp32 re-scan of the winning 32-col tile from
    //      GLOBAL with the proven fmaf chain; first-index argmin (strict <),
    //      xy gather, threshold.
    float sum = 0.0f;
    for (int q = 0; q < 2; ++q) {
        int n = tid * 2 + q;
        int ct = sCt[n];
        float thr = sThr[n];
        const float* pr = rowsrc + (size_t)n * FD;
        float t0 = fmaf(pr[5], s5, m5);
        float t1 = fmaf(pr[6], s6, m6);
        float t2 = fmaf(pr[7], s7, m7);
        float t3 = fmaf(pr[8], s8, m8);
        float vx = -0.5f * t0, vy = -0.5f * t1, vz = -0.5f * t2, vw = -0.5f * t3;
        float best = 3.0e38f;
        int bidx = 0;
        const int mbase = ct * 32;
#pragma unroll 4
        for (int j = 0; j < 32; ++j) {
            const float* pc = colsrc + (size_t)(mbase + j) * FD;
            float c0 = fmaf(pc[5], s5, m5);
            float c1 = fmaf(pc[6], s6, m6);
            float c2 = fmaf(pc[7], s7, m7);
            float c3 = fmaf(pc[8], s8, m8);
            float cs = 0.25f * (c0 * c0 + c1 * c1 + c2 * c2 + c3 * c3);
            float dd = fmaf(vx, c0, cs);
            dd = fmaf(vy, c1, dd);
            dd = fmaf(vz, c2, dd);
            dd = fmaf(vw, c3, dd);
            if (dd < best) { best = dd; bidx = mbase + j; }  // first idx on ties
        }
        const float* pw = colsrc + (size_t)bidx * FD;
        float gx = fmaf(pw[0], std0, mean0);
        float gy = fmaf(pw[1], std1, mean1);
        float ax = fmaf(pr[0], std0, mean0);
        float ay = fmaf(pr[1], std1, mean1);
        float dx = ax - gx;
        float dy = ay - gy;
        float dist = sqrtf(dx * dx + dy * dy);
        if (best > thr) dist = 1.0f;     // min_d > LATENT_DIST_THRESHOLD
        sum += dist;
    }

    // ---- Reduce: wave shuffle, cross-wave LDS, one atomic per block.
    for (int o = 32; o > 0; o >>= 1) sum += __shfl_down(sum, o, 64);
    if ((tid & 63) == 0) red[tid >> 6] = sum;
    __syncthreads();
    if (tid == 0) {
        float s = red[0] + red[1] + red[2] + red[3]
                + red[4] + red[5] + red[6] + red[7];
        // out[b] = -(sum over 4 views x 2 dirs x 1024 rows) / 8192
        atomicAdd(&out[bid >> 3], s * (-1.0f / 8192.0f));
    }
}

extern "C" void kernel_launch(void* const* d_in, const int* in_sizes, int n_in,
                              void* d_out, int out_size, void* d_ws, size_t ws_size,
                              hipStream_t stream)
{
    const float* ag = (const float*)d_in[0];   // achieved_goal (128,4,1024,10)
    const float* dg = (const float*)d_in[1];   // desired_goal  (128,4,1024,10)
    const float* nm = (const float*)d_in[2];   // norm_mean (10,)
    const float* ns = (const float*)d_in[3];   // norm_std  (10,)

    hipMemsetAsync(d_out, 0, BSZ * sizeof(float), stream);   // out is accumulated
    chamfer_pairs<<<BSZ * 4 * 2, TPB, 0, stream>>>(ag, dg, nm, ns, (float*)d_out);
}

// Round 5
// 172.165 us; speedup vs baseline: 1.2921x; 1.0210x over previous
//
#include <hip/hip_runtime.h>
#include <cstdint>
#include <cstddef>

#define NP  1024
#define FD  10
#define BSZ 128
#define TPB 512   // 8 waves; each wave owns 128 rows (4 row-tiles of 32)
#define NW  8
#define RT  4     // row-tiles per wave

// One block per (pair, dir): bid = pair*2 + d.
//   d=0: rows = state(ag), cols = goal(dg)   (reward_s2g)
//   d=1: rows = goal(dg),  cols = state(ag)  (reward_g2s)
//
// R5 = R4 MFMA numerics + LDS-resident epilogue (kill the scattered global
// rescan, which TA-throughput-bound the kernel at ~40-60 us/CU).
// d(n,m) = cs_m - 2 r_n . c_m on the matrix pipe via bf16 split-3 limbs in
// K=32 (two chained 32x32x16 bf16 MFMAs). Term set IDENTICAL to R2-R4
// (absmax 0.0 x3): ChRh, CmRh, ClRh, ChRm, CmRm, ChRl, CmRl + cs split-3.
// LDS: 3 bf16 planes (48 KB) + fp32 col plane {t0..t3,cs} stride-6 (24 KB).
// Pass 1 tracks (min, ct) per REG-QUAD: quad gi of the f32x16 acc covers
// contiguous abs cols ct*32 + 8*gi + 4*hh + {0..3} (C/D mapping m74/m101:
// row=(reg&3)+8*(reg>>2)+4*(lane>>5)). Merge 8 disjoint candidates by
// lexicographic (val, base) -> first-index tie semantics preserved. Epilogue
// rescans only the winning 4 cols from LDS in fp32 (proven chain, ascending
// strict <), winner xy via one tiny global gather per row.
typedef __attribute__((ext_vector_type(8)))  __bf16 bf16x8;
typedef __attribute__((ext_vector_type(16))) float  f32x16;

__device__ inline unsigned int pk2(__bf16 a, __bf16 b) {
    union { __bf16 h; unsigned short u; } ua, ub;
    ua.h = a; ub.h = b;
    return (unsigned int)ua.u | ((unsigned int)ub.u << 16);
}

__device__ inline void split3(float x, __bf16& h, __bf16& m, __bf16& l) {
    h = (__bf16)x;
    float r1 = x - (float)h;    // exact (h carries x's exponent, 8-bit mantissa)
    m = (__bf16)r1;
    float r2 = r1 - (float)m;   // exact
    l = (__bf16)r2;
}

extern "C" __global__ __launch_bounds__(TPB, 4)
void chamfer_pairs(const float* __restrict__ ag, const float* __restrict__ dg,
                   const float* __restrict__ nmean, const float* __restrict__ nstd,
                   float* __restrict__ out /* [BSZ], pre-zeroed */)
{
    __shared__ __align__(16) unsigned int ldsA[3 * NP * 4];  // 48 KB bf16 planes
    __shared__ __align__(8)  float        ldsF[NP * 6];      // 24 KB fp32 {t0..t3,cs,pad}
    __shared__ float red[NW];

    const int bid  = blockIdx.x;        // 0..1023
    const int pair = bid >> 1;
    const int d    = bid & 1;
    const int tid  = threadIdx.x;
    const int wv   = tid >> 6;          // wave 0..7
    const int l    = tid & 63;
    const int ln   = l & 31;            // lane's row slot / col slot
    const int hh   = l >> 5;            // k-half owner

    const float* rowsrc = ((d == 0) ? ag : dg) + (size_t)pair * (NP * FD);
    const float* colsrc = ((d == 0) ? dg : ag) + (size_t)pair * (NP * FD);

    // -2*(std, mean) for vis features 5..8 (uniform -> scalar regs).
    const float s5 = -2.0f * nstd[5], m5 = -2.0f * nmean[5];
    const float s6 = -2.0f * nstd[6], m6 = -2.0f * nmean[6];
    const float s7 = -2.0f * nstd[7], m7 = -2.0f * nmean[7];
    const float s8 = -2.0f * nstd[8], m8 = -2.0f * nmean[8];
    const float std0 = nstd[0], mean0 = nmean[0];
    const float std1 = nstd[1], mean1 = nmean[1];

    // ---- Stage columns: C = t = fmaf(raw,-2s,-2m) (= -2c, proven chain),
    //      cs = 0.25*dot(t,t); split-3 into the 3 bf16 K-layout planes AND
    //      fp32 copies into ldsF for the epilogue rescan.
    for (int m = tid; m < NP; m += TPB) {
        const float* p = colsrc + (size_t)m * FD;
        float t0 = fmaf(p[5], s5, m5);
        float t1 = fmaf(p[6], s6, m6);
        float t2 = fmaf(p[7], s7, m7);
        float t3 = fmaf(p[8], s8, m8);
        float cs = 0.25f * (t0 * t0 + t1 * t1 + t2 * t2 + t3 * t3);
        __bf16 ch0, cm0, cl0, ch1, cm1, cl1, ch2, cm2, cl2, ch3, cm3, cl3;
        __bf16 qh, qm, ql;
        split3(t0, ch0, cm0, cl0);
        split3(t1, ch1, cm1, cl1);
        split3(t2, ch2, cm2, cl2);
        split3(t3, ch3, cm3, cl3);
        split3(cs, qh, qm, ql);
        const __bf16 z = (__bf16)0.0f;
        unsigned int chA = pk2(ch0, ch1), chB = pk2(ch2, ch3);
        unsigned int cmA = pk2(cm0, cm1), cmB = pk2(cm2, cm3);
        unsigned int clA = pk2(cl0, cl1), clB = pk2(cl2, cl3);
        uint4* pl = (uint4*)ldsA;
        pl[0 * NP + m] = make_uint4(chA, chB, cmA, cmB);            // P0 = [Ch|Cm]
        pl[1 * NP + m] = make_uint4(clA, clB, chA, chB);            // P1 = [Cl|Ch]
        pl[2 * NP + m] = make_uint4(cmA, cmB, pk2(qh, qm), pk2(ql, z)); // P2 = [Cm|cs3,0]
        float* f = ldsF + m * 6;
        f[0] = t0; f[1] = t1; f[2] = t2; f[3] = t3; f[4] = cs;
    }

    // ---- Rows: split-3 of r = -0.5*t (proven lineage); B fragments per
    //      k-half; threshold rthr = 6 - 0.25*dot(t,t).
    bf16x8 B1[RT], B2[RT];
    float  rthr[RT];
    const __bf16 kone = (__bf16)1.0f;
    const __bf16 kzb  = (__bf16)0.0f;
#pragma unroll
    for (int rt = 0; rt < RT; ++rt) {
        int n = wv * 128 + rt * 32 + ln;
        const float* p = rowsrc + (size_t)n * FD;
        float t0 = fmaf(p[5], s5, m5);
        float t1 = fmaf(p[6], s6, m6);
        float t2 = fmaf(p[7], s7, m7);
        float t3 = fmaf(p[8], s8, m8);
        float rss = 0.25f * (t0 * t0 + t1 * t1 + t2 * t2 + t3 * t3);
        rthr[rt] = 6.0f - rss;
        float r0 = -0.5f * t0, r1 = -0.5f * t1, r2 = -0.5f * t2, r3 = -0.5f * t3;
        __bf16 rh0, rm0, rl0, rh1, rm1, rl1, rh2, rm2, rl2, rh3, rm3, rl3;
        split3(r0, rh0, rm0, rl0);
        split3(r1, rh1, rm1, rl1);
        split3(r2, rh2, rm2, rl2);
        split3(r3, rh3, rm3, rl3);
        // MFMA1: K0-7 = Ch.Rh, Cm.Rh ; K8-15 = Ch.Rm, Cm.Rm  (A = P0 both halves)
        __bf16 p0 = hh ? rm0 : rh0;
        __bf16 p1 = hh ? rm1 : rh1;
        __bf16 p2 = hh ? rm2 : rh2;
        __bf16 p3 = hh ? rm3 : rh3;
        bf16x8 b1;
        b1[0] = p0; b1[1] = p1; b1[2] = p2; b1[3] = p3;
        b1[4] = p0; b1[5] = p1; b1[6] = p2; b1[7] = p3;
        // MFMA2: K0-7 = Cl.Rh, Ch.Rl (A=P1) ; K8-15 = Cm.Rl, cs*1 (A=P2)
        __bf16 q0 = hh ? rl0 : rh0;
        __bf16 q1 = hh ? rl1 : rh1;
        __bf16 q2 = hh ? rl2 : rh2;
        __bf16 q3 = hh ? rl3 : rh3;
        bf16x8 b2;
        b2[0] = q0; b2[1] = q1; b2[2] = q2; b2[3] = q3;
        b2[4] = hh ? kone : rl0;
        b2[5] = hh ? kone : rl1;
        b2[6] = hh ? kone : rl2;
        b2[7] = hh ? kzb  : rl3;
        B1[rt] = b1; B2[rt] = b2;
    }
    __syncthreads();

    // ---- Pass 1: 32 col-tiles; 2 chained MFMAs -> 16 distances/lane, two
    //      concurrent rt-chains, per-QUAD (4 cols) min + (min, ct) tracker.
    f32x16 kz = {0.0f,0.0f,0.0f,0.0f,0.0f,0.0f,0.0f,0.0f,
                 0.0f,0.0f,0.0f,0.0f,0.0f,0.0f,0.0f,0.0f};
    float runmin[RT][4];
    int   runct[RT][4];
#pragma unroll
    for (int rt = 0; rt < RT; ++rt)
#pragma unroll
        for (int gi = 0; gi < 4; ++gi) { runmin[rt][gi] = 3.0e38f; runct[rt][gi] = 0; }

    const char* aBase1 = (const char*)ldsA + (size_t)ln * 16;                    // P0
    const char* aBase2 = (const char*)ldsA + (size_t)(1 + hh) * (NP * 16) + (size_t)ln * 16;

    for (int ct = 0; ct < 32; ++ct) {
        const bf16x8 a1 = *(const bf16x8*)(aBase1 + (size_t)ct * 512);
        const bf16x8 a2 = *(const bf16x8*)(aBase2 + (size_t)ct * 512);
#pragma unroll
        for (int rt = 0; rt < RT; rt += 2) {
            f32x16 accA = __builtin_amdgcn_mfma_f32_32x32x16_bf16(a1, B1[rt],     kz, 0, 0, 0);
            f32x16 accB = __builtin_amdgcn_mfma_f32_32x32x16_bf16(a1, B1[rt + 1], kz, 0, 0, 0);
            accA = __builtin_amdgcn_mfma_f32_32x32x16_bf16(a2, B2[rt],     accA, 0, 0, 0);
            accB = __builtin_amdgcn_mfma_f32_32x32x16_bf16(a2, B2[rt + 1], accB, 0, 0, 0);
#pragma unroll
            for (int gi = 0; gi < 4; ++gi) {   // quad gi = abs cols ct*32+8*gi+4*hh+{0..3}
                float g = fminf(fminf(accA[4 * gi], accA[4 * gi + 1]),
                                fminf(accA[4 * gi + 2], accA[4 * gi + 3]));
                bool lt = g < runmin[rt][gi];      // strict < keeps FIRST ct
                runmin[rt][gi] = fminf(runmin[rt][gi], g);
                runct[rt][gi]  = lt ? ct : runct[rt][gi];
            }
#pragma unroll
            for (int gi = 0; gi < 4; ++gi) {
                float g = fminf(fminf(accB[4 * gi], accB[4 * gi + 1]),
                                fminf(accB[4 * gi + 2], accB[4 * gi + 3]));
                bool lt = g < runmin[rt + 1][gi];
                runmin[rt + 1][gi] = fminf(runmin[rt + 1][gi], g);
                runct[rt + 1][gi]  = lt ? ct : runct[rt + 1][gi];
            }
        }
    }

    // ---- Merge the 8 disjoint quad-candidates per row by lexicographic
    //      (val, abs base) -- contiguous disjoint ranges make base order =
    //      column order, preserving reference first-index tie semantics.
    //      Then epilogue: lane handles its 2 assigned rows (hh-split), 4-col
    //      fp32 rescan from LDS (proven chain, ascending strict <).
    float sum = 0.0f;
#pragma unroll
    for (int rt = 0; rt < RT; ++rt) {
        float bv = runmin[rt][0];
        int   bc = runct[rt][0] * 32 + 4 * hh;
#pragma unroll
        for (int gi = 1; gi < 4; ++gi) {
            float v = runmin[rt][gi];
            int   c = runct[rt][gi] * 32 + 8 * gi + 4 * hh;
            bool take = (v < bv) || (v == bv && c < bc);
            bv = take ? v : bv;
            bc = take ? c : bc;
        }
        float ov = __shfl_xor(bv, 32);
        int   oc = __shfl_xor(bc, 32);
        bool take = (ov < bv) || (ov == bv && oc < bc);
        bv = take ? ov : bv;
        bc = take ? oc : bc;

        if ((rt >> 1) == hh) {               // hh=0 -> rt 0,1 ; hh=1 -> rt 2,3
            int n = wv * 128 + rt * 32 + ln;
            const float* pr = rowsrc + (size_t)n * FD;
            float t0 = fmaf(pr[5], s5, m5);
            float t1 = fmaf(pr[6], s6, m6);
            float t2 = fmaf(pr[7], s7, m7);
            float t3 = fmaf(pr[8], s8, m8);
            float vx = -0.5f * t0, vy = -0.5f * t1, vz = -0.5f * t2, vw = -0.5f * t3;
            float best = 3.0e38f;
            int   sel  = 0;
            const float* cf = ldsF + (size_t)bc * 6;
#pragma unroll
            for (int j = 0; j < 4; ++j) {
                float c0 = cf[j * 6 + 0];
                float c1 = cf[j * 6 + 1];
                float c2 = cf[j * 6 + 2];
                float c3 = cf[j * 6 + 3];
                float cs = cf[j * 6 + 4];
                float dd = fmaf(vx, c0, cs);
                dd = fmaf(vy, c1, dd);
                dd = fmaf(vz, c2, dd);
                dd = fmaf(vw, c3, dd);
                bool ltj = dd < best;        // ascending j + strict < = first idx
                best = fminf(best, dd);
                sel  = ltj ? j : sel;
            }
            int idx = bc + sel;
            const float* pw = colsrc + (size_t)idx * FD;
            float gx = fmaf(pw[0], std0, mean0);
            float gy = fmaf(pw[1], std1, mean1);
            float ax = fmaf(pr[0], std0, mean0);
            float ay = fmaf(pr[1], std1, mean1);
            float dx = ax - gx;
            float dy = ay - gy;
            float dist = sqrtf(dx * dx + dy * dy);
            if (best > rthr[rt]) dist = 1.0f;   // min_d > LATENT_DIST_THRESHOLD
            sum += dist;
        }
    }

    // ---- Reduce: wave shuffle, cross-wave LDS, one atomic per block.
    for (int o = 32; o > 0; o >>= 1) sum += __shfl_down(sum, o, 64);
    if ((tid & 63) == 0) red[tid >> 6] = sum;
    __syncthreads();
    if (tid == 0) {
        float s = red[0] + red[1] + red[2] + red[3]
                + red[4] + red[5] + red[6] + red[7];
        // out[b] = -(sum over 4 views x 2 dirs x 1024 rows) / 8192
        atomicAdd(&out[bid >> 3], s * (-1.0f / 8192.0f));
    }
}

extern "C" void kernel_launch(void* const* d_in, const int* in_sizes, int n_in,
                              void* d_out, int out_size, void* d_ws, size_t ws_size,
                              hipStream_t stream)
{
    const float* ag = (const float*)d_in[0];   // achieved_goal (128,4,1024,10)
    const float* dg = (const float*)d_in[1];   // desired_goal  (128,4,1024,10)
    const float* nm = (const float*)d_in[2];   // norm_mean (10,)
    const float* ns = (const float*)d_in[3];   // norm_std  (10,)

    hipMemsetAsync(d_out, 0, BSZ * sizeof(float), stream);   // out is accumulated
    chamfer_pairs<<<BSZ * 4 * 2, TPB, 0, stream>>>(ag, dg, nm, ns, (float*)d_out);
}

// Round 6
// 169.990 us; speedup vs baseline: 1.3086x; 1.0128x over previous
//
#include <hip/hip_runtime.h>
#include <cstdint>
#include <cstddef>

#define NP  1024
#define FD  10
#define BSZ 128
#define TPB 512   // 8 waves; each wave owns 128 rows (4 row-tiles of 32)
#define NW  8
#define RT  4     // row-tiles per wave

// One block per (pair, dir): bid = pair*2 + d.
//   d=0: rows = state(ag), cols = goal(dg)   (reward_s2g)
//   d=1: rows = goal(dg),  cols = state(ag)  (reward_g2s)
//
// R6 = R4 tile-level tracking (cheapest pass-1 VALU) + R5 LDS-resident
// epilogue (no scattered global rescan) + a1/a2 prefetch (hide LDS latency
// under the min-trees).
// d(n,m) = cs_m - 2 r_n . c_m on the matrix pipe via bf16 split-3 limbs in
// K=32 (two chained 32x32x16 bf16 MFMAs). Term set IDENTICAL to R2-R5
// (absmax 0.0 x4): ChRh, CmRh, ClRh, ChRm, CmRm, ChRl, CmRl + cs split-3.
// LDS planes (48 KB):
//   P0 = [Ch|Cm]  -- MFMA1, BOTH k-halves (B supplies Rh then Rm)
//   P1 = [Cl|Ch]  -- MFMA2 k-half 0       (B supplies Rh then Rl)
//   P2 = [Cm|csh,csm,csl,0] -- MFMA2 k-half 1 (B supplies Rl then 1,1,1,0)
// + fp32 col plane cvisF(float4)/csF(float) 20 KB (R0-proven layout, b128).
// Pass 1: per ct, 2 chained MFMAs x RT -> 16 distances/lane; 8-op min3 tree
// -> tile min; (min, ct) tracker, strict < keeps FIRST tile. Lane covers the
// hh-interleaved 16 of the tile's 32 cols; shfl_xor(32) lexicographic merge
// completes the tile. Epilogue: fp32 rescan of the winning tile's 32 cols
// from LDS (identical values/chain to the proven global rescan; ascending j,
// strict < = reference first-index argmin), xy gather, threshold.
typedef __attribute__((ext_vector_type(8)))  __bf16 bf16x8;
typedef __attribute__((ext_vector_type(16))) float  f32x16;

__device__ inline unsigned int pk2(__bf16 a, __bf16 b) {
    union { __bf16 h; unsigned short u; } ua, ub;
    ua.h = a; ub.h = b;
    return (unsigned int)ua.u | ((unsigned int)ub.u << 16);
}

__device__ inline void split3(float x, __bf16& h, __bf16& m, __bf16& l) {
    h = (__bf16)x;
    float r1 = x - (float)h;    // exact (h carries x's exponent, 8-bit mantissa)
    m = (__bf16)r1;
    float r2 = r1 - (float)m;   // exact
    l = (__bf16)r2;
}

__device__ inline float min3f(float a, float b, float c) {
    return fminf(fminf(a, b), c);   // fuses to v_min3_f32; order-invariant exact
}

extern "C" __global__ __launch_bounds__(TPB, 4)
void chamfer_pairs(const float* __restrict__ ag, const float* __restrict__ dg,
                   const float* __restrict__ nmean, const float* __restrict__ nstd,
                   float* __restrict__ out /* [BSZ], pre-zeroed */)
{
    __shared__ __align__(16) unsigned int ldsA[3 * NP * 4];  // 48 KB bf16 planes
    __shared__ __align__(16) float4       cvisF[NP];         // 16 KB fp32 {t0..t3}
    __shared__               float        csF[NP];           //  4 KB fp32 cs
    __shared__ float red[NW];

    const int bid  = blockIdx.x;        // 0..1023
    const int pair = bid >> 1;
    const int d    = bid & 1;
    const int tid  = threadIdx.x;
    const int wv   = tid >> 6;          // wave 0..7
    const int l    = tid & 63;
    const int ln   = l & 31;            // lane's row slot / col slot
    const int hh   = l >> 5;            // k-half owner

    const float* rowsrc = ((d == 0) ? ag : dg) + (size_t)pair * (NP * FD);
    const float* colsrc = ((d == 0) ? dg : ag) + (size_t)pair * (NP * FD);

    // -2*(std, mean) for vis features 5..8 (uniform -> scalar regs).
    const float s5 = -2.0f * nstd[5], m5 = -2.0f * nmean[5];
    const float s6 = -2.0f * nstd[6], m6 = -2.0f * nmean[6];
    const float s7 = -2.0f * nstd[7], m7 = -2.0f * nmean[7];
    const float s8 = -2.0f * nstd[8], m8 = -2.0f * nmean[8];
    const float std0 = nstd[0], mean0 = nmean[0];
    const float std1 = nstd[1], mean1 = nmean[1];

    // ---- Stage columns: C = t = fmaf(raw,-2s,-2m) (= -2c, proven chain),
    //      cs = 0.25*dot(t,t); split-3 into the 3 bf16 K-layout planes AND
    //      fp32 copies (float4 + float, conflict-light) for the epilogue.
    for (int m = tid; m < NP; m += TPB) {
        const float* p = colsrc + (size_t)m * FD;
        float t0 = fmaf(p[5], s5, m5);
        float t1 = fmaf(p[6], s6, m6);
        float t2 = fmaf(p[7], s7, m7);
        float t3 = fmaf(p[8], s8, m8);
        float cs = 0.25f * (t0 * t0 + t1 * t1 + t2 * t2 + t3 * t3);
        __bf16 ch0, cm0, cl0, ch1, cm1, cl1, ch2, cm2, cl2, ch3, cm3, cl3;
        __bf16 qh, qm, ql;
        split3(t0, ch0, cm0, cl0);
        split3(t1, ch1, cm1, cl1);
        split3(t2, ch2, cm2, cl2);
        split3(t3, ch3, cm3, cl3);
        split3(cs, qh, qm, ql);
        const __bf16 z = (__bf16)0.0f;
        unsigned int chA = pk2(ch0, ch1), chB = pk2(ch2, ch3);
        unsigned int cmA = pk2(cm0, cm1), cmB = pk2(cm2, cm3);
        unsigned int clA = pk2(cl0, cl1), clB = pk2(cl2, cl3);
        uint4* pl = (uint4*)ldsA;
        pl[0 * NP + m] = make_uint4(chA, chB, cmA, cmB);            // P0 = [Ch|Cm]
        pl[1 * NP + m] = make_uint4(clA, clB, chA, chB);            // P1 = [Cl|Ch]
        pl[2 * NP + m] = make_uint4(cmA, cmB, pk2(qh, qm), pk2(ql, z)); // P2 = [Cm|cs3,0]
        cvisF[m] = make_float4(t0, t1, t2, t3);
        csF[m]   = cs;
    }

    // ---- Rows: split-3 of r = -0.5*t (proven lineage); B fragments per
    //      k-half; threshold rthr = 6 - 0.25*dot(t,t).
    bf16x8 B1[RT], B2[RT];
    float  rthr[RT];
    const __bf16 kone = (__bf16)1.0f;
    const __bf16 kzb  = (__bf16)0.0f;
#pragma unroll
    for (int rt = 0; rt < RT; ++rt) {
        int n = wv * 128 + rt * 32 + ln;
        const float* p = rowsrc + (size_t)n * FD;
        float t0 = fmaf(p[5], s5, m5);
        float t1 = fmaf(p[6], s6, m6);
        float t2 = fmaf(p[7], s7, m7);
        float t3 = fmaf(p[8], s8, m8);
        float rss = 0.25f * (t0 * t0 + t1 * t1 + t2 * t2 + t3 * t3);
        rthr[rt] = 6.0f - rss;
        float r0 = -0.5f * t0, r1 = -0.5f * t1, r2 = -0.5f * t2, r3 = -0.5f * t3;
        __bf16 rh0, rm0, rl0, rh1, rm1, rl1, rh2, rm2, rl2, rh3, rm3, rl3;
        split3(r0, rh0, rm0, rl0);
        split3(r1, rh1, rm1, rl1);
        split3(r2, rh2, rm2, rl2);
        split3(r3, rh3, rm3, rl3);
        // MFMA1: K0-7 = Ch.Rh, Cm.Rh ; K8-15 = Ch.Rm, Cm.Rm  (A = P0 both halves)
        __bf16 p0 = hh ? rm0 : rh0;
        __bf16 p1 = hh ? rm1 : rh1;
        __bf16 p2 = hh ? rm2 : rh2;
        __bf16 p3 = hh ? rm3 : rh3;
        bf16x8 b1;
        b1[0] = p0; b1[1] = p1; b1[2] = p2; b1[3] = p3;
        b1[4] = p0; b1[5] = p1; b1[6] = p2; b1[7] = p3;
        // MFMA2: K0-7 = Cl.Rh, Ch.Rl (A=P1) ; K8-15 = Cm.Rl, cs*1 (A=P2)
        __bf16 q0 = hh ? rl0 : rh0;
        __bf16 q1 = hh ? rl1 : rh1;
        __bf16 q2 = hh ? rl2 : rh2;
        __bf16 q3 = hh ? rl3 : rh3;
        bf16x8 b2;
        b2[0] = q0; b2[1] = q1; b2[2] = q2; b2[3] = q3;
        b2[4] = hh ? kone : rl0;
        b2[5] = hh ? kone : rl1;
        b2[6] = hh ? kone : rl2;
        b2[7] = hh ? kzb  : rl3;
        B1[rt] = b1; B2[rt] = b2;
    }
    __syncthreads();

    // ---- Pass 1: 32 col-tiles; per ct: prefetch next a1/a2, 2 chained MFMAs
    //      x RT (two concurrent rt-chains), 8-op min3 tree -> tile min,
    //      (min, ct) tracker with strict < (keeps FIRST tile).
    f32x16 kz = {0.0f,0.0f,0.0f,0.0f,0.0f,0.0f,0.0f,0.0f,
                 0.0f,0.0f,0.0f,0.0f,0.0f,0.0f,0.0f,0.0f};
    float runmin[RT];
    int   runct[RT];
#pragma unroll
    for (int rt = 0; rt < RT; ++rt) { runmin[rt] = 3.0e38f; runct[rt] = 0; }

    const char* aBase1 = (const char*)ldsA + (size_t)ln * 16;                    // P0
    const char* aBase2 = (const char*)ldsA + (size_t)(1 + hh) * (NP * 16) + (size_t)ln * 16;

    bf16x8 a1 = *(const bf16x8*)(aBase1);
    bf16x8 a2 = *(const bf16x8*)(aBase2);
    for (int ct = 0; ct < 32; ++ct) {
        const int ctn = (ct + 1) & 31;                     // harmless wrap at 31
        bf16x8 a1n = *(const bf16x8*)(aBase1 + (size_t)ctn * 512);
        bf16x8 a2n = *(const bf16x8*)(aBase2 + (size_t)ctn * 512);
#pragma unroll
        for (int rt = 0; rt < RT; rt += 2) {
            f32x16 accA = __builtin_amdgcn_mfma_f32_32x32x16_bf16(a1, B1[rt],     kz, 0, 0, 0);
            f32x16 accB = __builtin_amdgcn_mfma_f32_32x32x16_bf16(a1, B1[rt + 1], kz, 0, 0, 0);
            accA = __builtin_amdgcn_mfma_f32_32x32x16_bf16(a2, B2[rt],     accA, 0, 0, 0);
            accB = __builtin_amdgcn_mfma_f32_32x32x16_bf16(a2, B2[rt + 1], accB, 0, 0, 0);
            {
                float u0 = min3f(accA[0],  accA[1],  accA[2]);
                float u1 = min3f(accA[3],  accA[4],  accA[5]);
                float u2 = min3f(accA[6],  accA[7],  accA[8]);
                float u3 = min3f(accA[9],  accA[10], accA[11]);
                float u4 = min3f(accA[12], accA[13], accA[14]);
                float mn = fminf(min3f(u0, u1, u2), min3f(u3, u4, accA[15]));
                bool lt = mn < runmin[rt];
                runmin[rt] = fminf(runmin[rt], mn);
                runct[rt]  = lt ? ct : runct[rt];
            }
            {
                float u0 = min3f(accB[0],  accB[1],  accB[2]);
                float u1 = min3f(accB[3],  accB[4],  accB[5]);
                float u2 = min3f(accB[6],  accB[7],  accB[8]);
                float u3 = min3f(accB[9],  accB[10], accB[11]);
                float u4 = min3f(accB[12], accB[13], accB[14]);
                float mn = fminf(min3f(u0, u1, u2), min3f(u3, u4, accB[15]));
                bool lt = mn < runmin[rt + 1];
                runmin[rt + 1] = fminf(runmin[rt + 1], mn);
                runct[rt + 1]  = lt ? ct : runct[rt + 1];
            }
        }
        a1 = a1n; a2 = a2n;
    }

    // ---- Merge k-halves (lane covers the hh-interleaved 16 of each tile's
    //      32 cols): shfl_xor(32) lexicographic (val, ct) -> full-tile winner.
    //      Then epilogue: lane handles its 2 assigned rows ((rt>>1)==hh),
    //      fp32 rescan of the winning tile's 32 cols FROM LDS (identical
    //      values and fmaf chain as the proven global rescan; ascending j +
    //      strict < = reference first-index argmin), xy gather, threshold.
    float sum = 0.0f;
#pragma unroll
    for (int rt = 0; rt < RT; ++rt) {
        float bv = runmin[rt];
        int   bc = runct[rt];
        float ov = __shfl_xor(bv, 32);
        int   oc = __shfl_xor(bc, 32);
        bool take = (ov < bv) || (ov == bv && oc < bc);
        bv = take ? ov : bv;
        bc = take ? oc : bc;

        if ((rt >> 1) == hh) {               // hh=0 -> rt 0,1 ; hh=1 -> rt 2,3
            int n = wv * 128 + rt * 32 + ln;
            const float* pr = rowsrc + (size_t)n * FD;
            float t0 = fmaf(pr[5], s5, m5);
            float t1 = fmaf(pr[6], s6, m6);
            float t2 = fmaf(pr[7], s7, m7);
            float t3 = fmaf(pr[8], s8, m8);
            float vx = -0.5f * t0, vy = -0.5f * t1, vz = -0.5f * t2, vw = -0.5f * t3;
            float best = 3.0e38f;
            int   sel  = 0;
            const int mbase = bc * 32;
#pragma unroll 4
            for (int j = 0; j < 32; ++j) {
                float4 c = cvisF[mbase + j];
                float cs = csF[mbase + j];
                float dd = fmaf(vx, c.x, cs);
                dd = fmaf(vy, c.y, dd);
                dd = fmaf(vz, c.z, dd);
                dd = fmaf(vw, c.w, dd);
                bool ltj = dd < best;        // ascending j + strict < = first idx
                best = fminf(best, dd);
                sel  = ltj ? j : sel;
            }
            int idx = mbase + sel;
            const float* pw = colsrc + (size_t)idx * FD;
            float gx = fmaf(pw[0], std0, mean0);
            float gy = fmaf(pw[1], std1, mean1);
            float ax = fmaf(pr[0], std0, mean0);
            float ay = fmaf(pr[1], std1, mean1);
            float dx = ax - gx;
            float dy = ay - gy;
            float dist = sqrtf(dx * dx + dy * dy);
            if (best > rthr[rt]) dist = 1.0f;   // min_d > LATENT_DIST_THRESHOLD
            sum += dist;
        }
    }

    // ---- Reduce: wave shuffle, cross-wave LDS, one atomic per block.
    for (int o = 32; o > 0; o >>= 1) sum += __shfl_down(sum, o, 64);
    if ((tid & 63) == 0) red[tid >> 6] = sum;
    __syncthreads();
    if (tid == 0) {
        float s = red[0] + red[1] + red[2] + red[3]
                + red[4] + red[5] + red[6] + red[7];
        // out[b] = -(sum over 4 views x 2 dirs x 1024 rows) / 8192
        atomicAdd(&out[bid >> 3], s * (-1.0f / 8192.0f));
    }
}

extern "C" void kernel_launch(void* const* d_in, const int* in_sizes, int n_in,
                              void* d_out, int out_size, void* d_ws, size_t ws_size,
                              hipStream_t stream)
{
    const float* ag = (const float*)d_in[0];   // achieved_goal (128,4,1024,10)
    const float* dg = (const float*)d_in[1];   // desired_goal  (128,4,1024,10)
    const float* nm = (const float*)d_in[2];   // norm_mean (10,)
    const float* ns = (const float*)d_in[3];   // norm_std  (10,)

    hipMemsetAsync(d_out, 0, BSZ * sizeof(float), stream);   // out is accumulated
    chamfer_pairs<<<BSZ * 4 * 2, TPB, 0, stream>>>(ag, dg, nm, ns, (float*)d_out);
}